// Round 8
// baseline (225.172 us; speedup 1.0000x reference)
//
#include <hip/hip_runtime.h>
#include <stdint.h>

typedef unsigned short u16;
typedef short short8 __attribute__((ext_vector_type(8)));
typedef short short4v __attribute__((ext_vector_type(4)));
typedef float float4v __attribute__((ext_vector_type(4)));
typedef float float16v __attribute__((ext_vector_type(16)));
typedef uint32_t uint2v __attribute__((ext_vector_type(2)));

#define HW 4096
#define QSCL 0.18033688011112042f   /* 0.125 * log2(e), folded into Q at conv time */

// async global->LDS DMA: per-lane global addr, LDS dest = wave-uniform base + lane*16
#define GLOAD_LDS(g, l) __builtin_amdgcn_global_load_lds( \
    (const __attribute__((address_space(1))) void*)(g),   \
    (__attribute__((address_space(3))) void*)(l), 16, 0, 0)

static __device__ __forceinline__ u16 f2bf(float f) {
  union { float f; uint32_t u; } v; v.f = f;
  uint32_t r = v.u + 0x7fffu + ((v.u >> 16) & 1u);
  return (u16)(r >> 16);
}

// packed f32x2 -> bf16x2 (RNE), single instruction; src0 -> low half
static __device__ __forceinline__ uint32_t pkbf(float a, float b) {
  uint32_t r;
  asm("v_cvt_pk_bf16_f32 %0, %1, %2" : "=v"(r) : "v"(a), "v"(b));
  return r;
}
// v_permlane32_swap_b32: a.hi32lanes <-> b.lo32lanes (both regs modified)
static __device__ __forceinline__ void plswap(uint32_t &a, uint32_t &b) {
  asm("v_permlane32_swap_b32 %0, %1" : "+v"(a), "+v"(b));
}

union PU { uint32_t u[4]; short8 v; };

// ---- kernel 1: x [4,256,4096] f32 -> Xtp [4,66,66,256] bf16 (spatially padded; halo pre-zeroed)
__global__ __launch_bounds__(256) void k_xt(const float* __restrict__ x, u16* __restrict__ Xtp) {
  __shared__ float t[32][33];
  const int b = blockIdx.z, c0 = blockIdx.y * 32, p0 = blockIdx.x * 32;
  const int tid = threadIdx.x;
  const int l8 = tid >> 5, lp = tid & 31;
#pragma unroll
  for (int i = 0; i < 4; i++) {
    int c = l8 + i * 8;
    t[c][lp] = x[(size_t)(b * 256 + c0 + c) * HW + p0 + lp];
  }
  __syncthreads();
#pragma unroll
  for (int i = 0; i < 4; i++) {
    int p = l8 + i * 8;
    int pp = p0 + p;
    int y = pp >> 6, xx = pp & 63;
    Xtp[((size_t)(b * 66 + y + 1) * 66 + (xx + 1)) * 256 + c0 + lp] = f2bf(t[lp][p]);
  }
}

// ---- kernel 2: repack weights -> Wt [9][384][256] bf16 (ci contiguous), bcat[384] f32
__global__ __launch_bounds__(256) void k_wprep(const float* __restrict__ qw, const float* __restrict__ qb,
    const float* __restrict__ kw, const float* __restrict__ kb,
    const float* __restrict__ vw, const float* __restrict__ vb,
    u16* __restrict__ Wt, float* __restrict__ bcat) {
  int tid = blockIdx.x * 256 + threadIdx.x;
  if (tid < 9 * 384 * 256) {
    int ci = tid & 255;
    int n = (tid >> 8) % 384;
    int off = tid / (384 * 256);
    float val;
    if (n < 64)       val = qw[(size_t)n * 2304 + ci * 9 + off];
    else if (n < 128) val = kw[(size_t)(n - 64) * 2304 + ci * 9 + off];
    else              val = vw[(size_t)(n - 128) * 2304 + ci * 9 + off];
    Wt[tid] = f2bf(val);
  }
  if (tid < 384) bcat[tid] = (tid < 64) ? qb[tid] : (tid < 128) ? kb[tid - 64] : vb[tid - 128];
}

// ---- kernel 3: fused QKV conv (proven structure; Q outputs pre-scaled by QSCL).
__global__ __launch_bounds__(256) void k_conv(const u16* __restrict__ Xtp,
    const u16* __restrict__ Wt, const float* __restrict__ bcat,
    u16* __restrict__ Qt, u16* __restrict__ Kt, u16* __restrict__ Vcf) {
  __shared__ __align__(16) u16 Als[2][128 * 64];   // 16 KB per buf [row pos][64 k]
  __shared__ __align__(16) u16 Bls[2][64 * 64];    // 8 KB per buf  [row ch ][64 k]
  const int tid = threadIdx.x;
  const int b = blockIdx.z, ct = blockIdx.y;       // ct: 0=Q, 1=K, 2..5=V slices
  const int p0 = blockIdx.x * 128, n0 = ct * 64;
  const int w = tid >> 6, lane = tid & 63, l16 = lane & 15, quad = lane >> 4;

  const int lr = lane >> 3, lcx = (lane & 7) ^ lr;
  const u16* ag[4];
#pragma unroll
  for (int g = 0; g < 4; g++) {
    const int pos = p0 + w * 32 + g * 8 + lr;
    const int py = pos >> 6, px = pos & 63;
    ag[g] = Xtp + ((size_t)(b * 66 + py) * 66 + px) * 256 + lcx * 8;
  }
  const u16* bg[2];
#pragma unroll
  for (int g = 0; g < 2; g++)
    bg[g] = Wt + (size_t)(n0 + w * 16 + g * 8 + lr) * 256 + lcx * 8;

  const int rx = l16 & 7;

  float4v acc[2][4];
  const float4v zz = {0.f, 0.f, 0.f, 0.f};
#pragma unroll
  for (int i = 0; i < 2; i++)
#pragma unroll
    for (int j = 0; j < 4; j++) acc[i][j] = zz;

#pragma unroll
  for (int g = 0; g < 4; g++) GLOAD_LDS(ag[g], &Als[0][(w * 32 + g * 8) * 64]);
#pragma unroll
  for (int g = 0; g < 2; g++) GLOAD_LDS(bg[g], &Bls[0][(w * 16 + g * 8) * 64]);
  __syncthreads();

  for (int ks = 0; ks < 36; ks++) {
    const int buf = ks & 1;
    if (ks + 1 < 36) {
      const int ksn = ks + 1, tap = ksn >> 2, cg = (ksn & 3) * 64;
      const int dy = (tap * 11) >> 5, dx = tap - dy * 3;
      const int aoff = (dy * 66 + dx) * 256 + cg;
      const size_t boff = (size_t)tap * 98304 + cg;
#pragma unroll
      for (int g = 0; g < 4; g++) GLOAD_LDS(ag[g] + aoff, &Als[buf ^ 1][(w * 32 + g * 8) * 64]);
#pragma unroll
      for (int g = 0; g < 2; g++) GLOAD_LDS(bg[g] + boff, &Bls[buf ^ 1][(w * 16 + g * 8) * 64]);
    }

    short8 af[2][2], bfv[4][2];
#pragma unroll
    for (int mt = 0; mt < 2; mt++)
#pragma unroll
      for (int kk = 0; kk < 2; kk++)
        af[mt][kk] = *(const short8*)&Als[buf][(w * 32 + mt * 16 + l16) * 64 + (((kk * 4 + quad) ^ rx) * 8)];
#pragma unroll
    for (int nt = 0; nt < 4; nt++)
#pragma unroll
      for (int kk = 0; kk < 2; kk++)
        bfv[nt][kk] = *(const short8*)&Bls[buf][(nt * 16 + l16) * 64 + (((kk * 4 + quad) ^ rx) * 8)];

    if (ct < 2) {
#pragma unroll
      for (int mt = 0; mt < 2; mt++)
#pragma unroll
        for (int nt = 0; nt < 4; nt++)
#pragma unroll
          for (int kk = 0; kk < 2; kk++)
            acc[mt][nt] = __builtin_amdgcn_mfma_f32_16x16x32_bf16(bfv[nt][kk], af[mt][kk], acc[mt][nt], 0, 0, 0);
    } else {
#pragma unroll
      for (int mt = 0; mt < 2; mt++)
#pragma unroll
        for (int nt = 0; nt < 4; nt++)
#pragma unroll
          for (int kk = 0; kk < 2; kk++)
            acc[mt][nt] = __builtin_amdgcn_mfma_f32_16x16x32_bf16(af[mt][kk], bfv[nt][kk], acc[mt][nt], 0, 0, 0);
    }
    __syncthreads();
  }

  if (ct < 2) {
    u16* base = (ct == 0) ? Qt : Kt;
    const float qs = (ct == 0) ? QSCL : 1.0f;
#pragma unroll
    for (int mt = 0; mt < 2; mt++) {
      const int p = p0 + w * 32 + mt * 16 + l16;
#pragma unroll
      for (int nt = 0; nt < 4; nt++) {
        const int nb = nt * 16 + quad * 4;
        short4v o;
#pragma unroll
        for (int r = 0; r < 4; r++) o[r] = (short)f2bf((acc[mt][nt][r] + bcat[ct * 64 + nb + r]) * qs);
        *(short4v*)(base + (size_t)(b * HW + p) * 64 + nb) = o;
      }
    }
  } else {
#pragma unroll
    for (int mt = 0; mt < 2; mt++) {
      const int pb = p0 + w * 32 + mt * 16 + quad * 4;
#pragma unroll
      for (int nt = 0; nt < 4; nt++) {
        const int cl = nt * 16 + l16;
        const int gc = (ct - 2) * 64 + cl;
        const float bias = bcat[ct * 64 + cl];
        short4v o;
#pragma unroll
        for (int r = 0; r < 4; r++) o[r] = (short)f2bf(acc[mt][nt][r] + bias);
        *(short4v*)(Vcf + (size_t)(b * 256 + gc) * HW + pb) = o;
      }
    }
  }
}

// ---- kernel 4: flash attention, R7 = R6's in-reg softmax + LINE-DENSE staging.
// R6 post-mortem: all structures ceiling at ~10.6 B/cyc/CU staging delivery;
// cause = 32-j V tiles read 64 B per 8-KB V row (half-used 128-B cache lines,
// 16 scattered lines per DMA). Fix: j-tile 64 -> V row segments = 128 B = full
// lines (m97/m201-class density, 22-47 B/cyc measured there; R1's 64-j V tiles
// hit 24 B/cyc). K moves to REGISTERS (R5-proven: contiguous 4-KB-span A-frags,
// dbuf'd via 2-unrolled loop) so LDS = 2 streams x 2 bufs x V[256c][64j]
// = 128 KB exactly. Counted vmcnt(8) (V DMAs issued before K loads; in-order
// retire => <=8 outstanding proves V landed) + raw s_barrier + sched_barrier
// pins. 8-chunk XOR swizzle on 128-B rows (R1's proven koff pattern on both
// sides) => conflict-free b128 reads. 32 iterations; numerics = R6 verified.
__global__ __launch_bounds__(256, 1) void k_attn(const u16* __restrict__ Qt,
    const u16* __restrict__ Kt, const u16* __restrict__ Vcf, float* __restrict__ out) {
  __shared__ __align__(16) u16 lds[65536];   // 128 KB: [jh 2][buf 2][c 256][j 64]

  const int tid = threadIdx.x;
  const int bid = blockIdx.x;
  const int b = bid & 3;                     // XCD k -> batch k&3 (L2 pin)
  const int q0 = (bid >> 2) * 64;
  const int w = tid >> 6, lane = tid & 63;
  const int l32 = lane & 31, half = lane >> 5;
  const int qa = w & 1, jh = w >> 1;         // wave: 32 q-rows (qa), j-half (jh)

  u16* Sv = lds + jh * 32768;                // this stream's V (2 bufs x 16384 u16)

  // V staging: 16 DMAs/wave/tile; 8 c-rows x 8 chunks(16B); global chunk=(lane&7)^lr
  const int lr = lane >> 3, lcx = (lane & 7) ^ lr;
  const char* vs0 = (const char*)Vcf + ((size_t)(b * 256 + qa * 128 + lr)) * 8192
                    + jh * 4096 + (size_t)lcx * 16;

  // K frags from global (A[m=j: l32][k=d: half*8+e], per ks slice +16 d)
  const u16* kq = Kt + ((size_t)(b * HW + jh * 2048 + l32)) * 64 + half * 8;

  // Q as B-operand: B[k=d: half*8+e (+16/ks)][n=i: l32], pre-scaled by QSCL
  short8 qf[4];
  {
    const u16* qp = Qt + ((size_t)(b * HW + q0 + qa * 32 + l32)) * 64 + half * 8;
#pragma unroll
    for (int ks = 0; ks < 4; ks++) qf[ks] = *(const short8*)(qp + ks * 16);
  }

  const int rx = l32 & 7;                    // V read chunk swizzle
  const int vrow = l32 * 64;                 // V read row base (u16)

  float16v of[8];
#pragma unroll
  for (int ct = 0; ct < 8; ct++)
#pragma unroll
    for (int r = 0; r < 16; r++) of[ct][r] = 0.f;
  float lp = 0.f;

  short8 kfA[2][4], kfB[2][4];

#define STAGEV(T, BUF) {                                                          \
    const char* vt = vs0 + (size_t)(T) * 128;                                     \
    u16* db = Sv + (BUF) * 16384 + qa * 8192;                                     \
    _Pragma("unroll") for (int g = 0; g < 16; g++)                                \
      GLOAD_LDS(vt + (size_t)g * 65536, db + g * 512);                            \
  }

#define LOADK(T, KF) {                                                            \
    const u16* kp = kq + (size_t)((T) & 31) * 4096;                               \
    _Pragma("unroll") for (int js = 0; js < 2; js++)                              \
      _Pragma("unroll") for (int ks = 0; ks < 4; ks++)                            \
        KF[js][ks] = *(const short8*)(kp + js * 2048 + ks * 16);                  \
  }

  // softmax + PV for one 32-j subtile (verified R6 math): s -> p -> pb0/pb1 -> 16 MFMA
#define SOFTPV(SS, VB, C0, C1) {                                                  \
    float p0 = exp2f(SS[0]),  p1 = exp2f(SS[1]),  p2 = exp2f(SS[2]),  p3 = exp2f(SS[3]);   \
    float p4 = exp2f(SS[4]),  p5 = exp2f(SS[5]),  p6 = exp2f(SS[6]),  p7 = exp2f(SS[7]);   \
    float p8 = exp2f(SS[8]),  p9 = exp2f(SS[9]),  pa = exp2f(SS[10]), pb_ = exp2f(SS[11]); \
    float pc = exp2f(SS[12]), pd = exp2f(SS[13]), pe = exp2f(SS[14]), pf = exp2f(SS[15]);  \
    lp += ((p0 + p1) + (p2 + p3)) + ((p4 + p5) + (p6 + p7))                       \
        + ((p8 + p9) + (pa + pb_)) + ((pc + pd) + (pe + pf));                     \
    uint32_t c0 = pkbf(p0, p1), c1 = pkbf(p2, p3), c2 = pkbf(p4, p5), c3 = pkbf(p6, p7);   \
    plswap(c0, c2); plswap(c1, c3);                                               \
    uint32_t d0 = pkbf(p8, p9), d1 = pkbf(pa, pb_), d2 = pkbf(pc, pd), d3 = pkbf(pe, pf);  \
    plswap(d0, d2); plswap(d1, d3);                                               \
    PU pA, pB;                                                                    \
    pA.u[0] = c0; pA.u[1] = c1; pA.u[2] = c2; pA.u[3] = c3;                       \
    pB.u[0] = d0; pB.u[1] = d1; pB.u[2] = d2; pB.u[3] = d3;                       \
    const int ca = (((C0) + half) ^ rx) * 8, cb = (((C1) + half) ^ rx) * 8;       \
    _Pragma("unroll") for (int ct = 0; ct < 8; ct++) {                            \
      short8 vfa = *(const short8*)&VB[vrow + ct * 2048 + ca];                    \
      of[ct] = __builtin_amdgcn_mfma_f32_32x32x16_bf16(vfa, pA.v, of[ct], 0, 0, 0); \
      short8 vfb = *(const short8*)&VB[vrow + ct * 2048 + cb];                    \
      of[ct] = __builtin_amdgcn_mfma_f32_32x32x16_bf16(vfb, pB.v, of[ct], 0, 0, 0); \
    }                                                                             \
  }

  // one tile: vmcnt(8) proves V(T) landed (V issued before K, in-order retire);
  // stage V(T+1) into freed buf; QK with KF; reload KF <- K(T+2); softmax+PV.
#define HALF_ITER(T, PAR, KF) {                                                   \
    asm volatile("s_waitcnt vmcnt(8)" ::: "memory");                              \
    __builtin_amdgcn_s_barrier();                                                 \
    __builtin_amdgcn_sched_barrier(0);                                            \
    STAGEV(((T) + 1) & 31, (PAR) ^ 1);                                            \
    __builtin_amdgcn_sched_barrier(0);                                            \
    float16v s0, s1;                                                              \
    _Pragma("unroll") for (int r = 0; r < 16; r++) { s0[r] = 0.f; s1[r] = 0.f; }  \
    _Pragma("unroll") for (int ks = 0; ks < 4; ks++) {                            \
      s0 = __builtin_amdgcn_mfma_f32_32x32x16_bf16(KF[0][ks], qf[ks], s0, 0, 0, 0); \
      s1 = __builtin_amdgcn_mfma_f32_32x32x16_bf16(KF[1][ks], qf[ks], s1, 0, 0, 0); \
    }                                                                             \
    LOADK((T) + 2, KF);                                                           \
    __builtin_amdgcn_sched_barrier(0);                                            \
    const u16* VB = Sv + (PAR) * 16384;                                           \
    SOFTPV(s0, VB, 0, 2);                                                         \
    SOFTPV(s1, VB, 4, 6);                                                         \
  }

  // ---- prologue: V(0) -> buf0; K frags for tiles 0 (A) and 1 (B)
  STAGEV(0, 0);
  __builtin_amdgcn_sched_barrier(0);
  LOADK(0, kfA);
  LOADK(1, kfB);

  for (int t = 0; t < 32; t += 2) {
    HALF_ITER(t, 0, kfA);
    HALF_ITER(t + 1, 1, kfB);
  }
#undef HALF_ITER
#undef SOFTPV
#undef LOADK
#undef STAGEV

  // ---- epilogue: combine j-halves via LDS; scale; store (R6-verified layout)
  lp += __shfl_xor(lp, 32);
  __syncthreads();
  float* Lf = (float*)lds + 16384;
  if (lane < 32) Lf[w * 32 + l32] = lp;
  float* Osh = (float*)lds + qa * 8192;
  if (jh) {
#pragma unroll
    for (int ct = 0; ct < 8; ct++)
#pragma unroll
      for (int r = 0; r < 16; r++)
        Osh[(ct * 32 + (r & 3) + 8 * (r >> 2) + 4 * half) * 32 + l32] = of[ct][r];
  }
  __syncthreads();
  if (!jh) {
    const float inv = 1.0f / (Lf[qa * 32 + l32] + Lf[(2 + qa) * 32 + l32]);
    float* ob = out + (size_t)(b * 256) * HW + q0 + qa * 32 + l32;
#pragma unroll
    for (int ct = 0; ct < 8; ct++)
#pragma unroll
      for (int r = 0; r < 16; r++) {
        const int c = ct * 32 + (r & 3) + 8 * (r >> 2) + 4 * half;
        ob[(size_t)c * HW] = (of[ct][r] + Osh[c * 32 + l32]) * inv;
      }
  }
}

extern "C" void kernel_launch(void* const* d_in, const int* in_sizes, int n_in,
                              void* d_out, int out_size, void* d_ws, size_t ws_size,
                              hipStream_t stream) {
  const float* x  = (const float*)d_in[0];
  const float* qw = (const float*)d_in[1];
  const float* qb = (const float*)d_in[2];
  const float* kw = (const float*)d_in[3];
  const float* kb = (const float*)d_in[4];
  const float* vw = (const float*)d_in[5];
  const float* vb = (const float*)d_in[6];
  float* out = (float*)d_out;
  char* ws = (char*)d_ws;
  u16*   Xtp = (u16*)(ws);
  u16*   Wt  = (u16*)(ws + 8921088);
  float* bc  = (float*)(ws + 10690560);
  u16*   Qt  = (u16*)(ws + 10692096);
  u16*   Kt  = (u16*)(ws + 12789248);
  u16*   Vcf = (u16*)(ws + 14886400);

  hipMemsetAsync(Xtp, 0, 8921088, stream);  // zero the spatial halo
  k_xt  <<<dim3(128, 8, 4), 256, 0, stream>>>(x, Xtp);
  k_wprep<<<3456, 256, 0, stream>>>(qw, qb, kw, kb, vw, vb, Wt, bc);
  k_conv<<<dim3(32, 6, 4), 256, 0, stream>>>(Xtp, Wt, bc, Qt, Kt, Vcf);
  k_attn<<<256, 256, 0, stream>>>(Qt, Kt, Vcf, out);
}